// Round 6
// baseline (172.794 us; speedup 1.0000x reference)
//
#include <hip/hip_runtime.h>
#include <hip/hip_bf16.h>
#include <math.h>

#define LEAKY 0.01f
#define B_    2048
#define F_    512
#define H_    64
#define K_    8
#define D_    128
#define ASR_  128
#define MM_   768
#define OUT_  256
#define PROJ_IN 66432          // 128+768+512*128
#define ZK    4992             // 896 + 512*8 (emb folded into proj_w)
#define NSPLIT 8               // gemm split-K factor

// ---------------- workspace layout (bytes) ----------------
// A0   : [B_][896]     bf16   @ 0            3,670,016   (asr|mm pre-bf16)
// Pf   : [F_][B_][8]   bf16   @ 3,670,016   16,777,216   (probs, f-major!)
// Wn   : [OUT_][ZK]    bf16   @ 20,447,232   2,555,904
// part : [8][B_][OUT_] fp32   @ 23,003,136  16,777,216
// total 39,780,352  (actual ws_size ~272 MB per poison WRITE_SIZE)

typedef unsigned short u16;
typedef u16   u16x4 __attribute__((ext_vector_type(4)));
typedef u16   u16x8 __attribute__((ext_vector_type(8)));
typedef short s16x8 __attribute__((ext_vector_type(8)));
typedef float f32x4 __attribute__((ext_vector_type(4)));

__device__ __forceinline__ u16 f2bf(float x) {   // RNE float->bf16 bits
  unsigned int u = __float_as_uint(x);
  u += 0x7fffu + ((u >> 16) & 1u);
  return (u16)(u >> 16);
}

// ---------------------------------------------------------------------------
// Fused producers. Heterogeneous blocks (order: longest first):
//   bid < 2048          : wn_g   (feature f, 64 o-rows)          [HBM-bound]
//   2048 <= bid < 2560  : probs  (4 features x 512 rows, wave-uniform f)
//   2560 <= bid < 3456  : a0     (asr|mm -> bf16, 2048 elems)
//   3456 <= bid < 3680  : wn_top (1024 elems)
#define PRODUCER_BLOCKS (2048 + 512 + 896 + 224)

__global__ __launch_bounds__(256) void producer_kernel(
    const float* __restrict__ stat, const float* __restrict__ w1,
    const float* __restrict__ b1v, const float* __restrict__ w2,
    const float* __restrict__ b2v, const float* __restrict__ tauv,
    const float* __restrict__ pw, const float* __restrict__ emb,
    const float* __restrict__ asr, const float* __restrict__ mm,
    u16* __restrict__ A0, u16* __restrict__ Pf, u16* __restrict__ Wn) {
  __shared__ __align__(16) char smem[20992];
  const int bid = blockIdx.x;
  const int t = threadIdx.x;

  if (bid < 2048) {
    // ---------------- wn_g: Wn[o][896+f*8+k] = sum_d emb[f,k,d]*pw[o,896+f*128+d]
    const int f = bid >> 2;
    const int o0 = (bid & 3) * 64;
    float* s_emb = (float*)smem;                      // 4 KB
    for (int i = t; i < K_ * D_; i += 256) s_emb[i] = emb[(size_t)f * K_ * D_ + i];
    __syncthreads();
    const int orow = t >> 2, dc = t & 3;              // quad reads 64B contiguous
    const float* src = pw + (size_t)(o0 + orow) * PROJ_IN + 896 + f * D_;
    float g[K_] = {0.f, 0.f, 0.f, 0.f, 0.f, 0.f, 0.f, 0.f};
    #pragma unroll
    for (int j = 0; j < 8; ++j) {
      const int d = dc * 4 + j * 16;
      float4 w = *(const float4*)(src + d);
      #pragma unroll
      for (int k = 0; k < K_; ++k) {
        float4 e = *(const float4*)(s_emb + k * D_ + d);
        g[k] = fmaf(w.x, e.x, g[k]);
        g[k] = fmaf(w.y, e.y, g[k]);
        g[k] = fmaf(w.z, e.z, g[k]);
        g[k] = fmaf(w.w, e.w, g[k]);
      }
    }
    #pragma unroll
    for (int k = 0; k < K_; ++k) {
      g[k] += __shfl_xor(g[k], 1);
      g[k] += __shfl_xor(g[k], 2);
    }
    if (dc == 0) {
      u16x8 hv;
      #pragma unroll
      for (int k = 0; k < K_; ++k) hv[k] = f2bf(g[k]);
      *(u16x8*)(Wn + (size_t)(o0 + orow) * ZK + 896 + f * K_) = hv;
    }
  } else if (bid < 2560) {
    // ---------------- probs: 4 features (1/wave, uniform) x 512 rows ----------
    const int pb = bid - 2048;
    const int f0 = (pb & 127) * 4;
    const int b0 = (pb >> 7) * 512;
    float* s_w1s = (float*)(smem);                    // [4][64]   1024 B
    float* s_b1  = (float*)(smem + 1024);             // [4][64]   1024 B
    float* s_w2  = (float*)(smem + 2048);             // [4][512]  8192 B
    float* s_b2  = (float*)(smem + 10240);            // [4][8]     128 B
    float* s_tau = (float*)(smem + 10368);            // [4][8]     128 B
    float* s_x   = (float*)(smem + 10496);            // [512] x stride5  10240 B
    {
      int fl = t >> 6, h = t & 63;                    // 256 thr = 4 feat x 64 h
      const float* wf = w1 + (size_t)(f0 + fl) * 192;
      s_w1s[fl * 64 + h] = wf[h] + wf[64 + h] + wf[128 + h];  // x3 identical copies
      s_b1[fl * 64 + h] = b1v[(size_t)(f0 + fl) * 64 + h];
    }
    for (int i = t; i < 4 * 512; i += 256) {
      int fl = i >> 9, idx = i & 511;
      s_w2[fl * 512 + idx] = w2[(size_t)(f0 + fl) * 512 + idx];
    }
    if (t < 32) {
      s_b2[t]  = b2v[f0 * 8 + t];
      s_tau[t] = tauv[f0 * 8 + t];
    }
    for (int p = 0; p < 8; ++p) {                     // coalesced stat tile
      int i = p * 256 + t;
      int r = i >> 2, fl = i & 3;
      float v = stat[(size_t)(b0 + r) * F_ + f0 + fl];
      s_x[r * 5 + fl] = (v >= 0.f) ? v : 0.f;         // NaN -> 0, neg -> 0
    }
    __syncthreads();

    const int w = t >> 6;                             // wave-uniform feature
    const int lane = t & 63;
    const float* w1p = s_w1s + w * 64;
    const float* b1p = s_b1 + w * 64;
    const float* w2p = s_w2 + w * 512;
    float x[8];
    #pragma unroll
    for (int p = 0; p < 8; ++p) x[p] = s_x[(lane + 64 * p) * 5 + w];
    float acc[8][8] = {{0.f}};
    #pragma unroll 4
    for (int i = 0; i < 64; ++i) {
      float wv = w1p[i], bv = b1p[i];                 // same-address broadcast
      float4 wa = *(const float4*)(w2p + i * 8);      // broadcast b128
      float4 wb = *(const float4*)(w2p + i * 8 + 4);
      #pragma unroll
      for (int p = 0; p < 8; ++p) {
        float h0 = fmaf(x[p], wv, bv);
        float h = fmaf(LEAKY, fminf(h0, 0.f), fmaxf(h0, 0.f));  // leaky
        acc[p][0] = fmaf(h, wa.x, acc[p][0]);
        acc[p][1] = fmaf(h, wa.y, acc[p][1]);
        acc[p][2] = fmaf(h, wa.z, acc[p][2]);
        acc[p][3] = fmaf(h, wa.w, acc[p][3]);
        acc[p][4] = fmaf(h, wb.x, acc[p][4]);
        acc[p][5] = fmaf(h, wb.y, acc[p][5]);
        acc[p][6] = fmaf(h, wb.z, acc[p][6]);
        acc[p][7] = fmaf(h, wb.w, acc[p][7]);
      }
    }
    #pragma unroll
    for (int p = 0; p < 8; ++p) {
      float s[K_];
      float m = -1e30f;
      #pragma unroll
      for (int k = 0; k < K_; ++k) {
        float v = acc[p][k] + s_b2[w * 8 + k];
        v = (v >= 0.f) ? v : LEAKY * v;
        v *= s_tau[w * 8 + k];
        s[k] = v;
        m = fmaxf(m, v);
      }
      float sum = 0.f;
      #pragma unroll
      for (int k = 0; k < K_; ++k) { s[k] = __expf(s[k] - m); sum += s[k]; }
      float inv = 1.f / sum;
      u16x8 hv;
      #pragma unroll
      for (int k = 0; k < K_; ++k) hv[k] = f2bf(s[k] * inv);
      // Pf[f][b][8]: 64 consecutive rows per wave -> fully coalesced 16B stores
      *(u16x8*)(Pf + ((size_t)(f0 + w) * B_ + b0 + lane + 64 * p) * 8) = hv;
    }
  } else if (bid < 3456) {
    // ---------------- a0: A0[b][j] = bf16(asr|mm), 8 elems/thread -------------
    const int item = bid - 2560;                      // 896 blocks x 2048 elems
    const int cidx = item * 256 + t;                  // chunk of 8; 112 chunks/row
    const int r = cidx / 112, c = cidx % 112;
    float4 v0, v1;
    if (c < 16) {
      const float* s = asr + (size_t)r * ASR_ + c * 8;
      v0 = *(const float4*)(s); v1 = *(const float4*)(s + 4);
    } else {
      const float* s = mm + (size_t)r * MM_ + (c - 16) * 8;
      v0 = *(const float4*)(s); v1 = *(const float4*)(s + 4);
    }
    u16x8 hv = {f2bf(v0.x), f2bf(v0.y), f2bf(v0.z), f2bf(v0.w),
                f2bf(v1.x), f2bf(v1.y), f2bf(v1.z), f2bf(v1.w)};
    *(u16x8*)(A0 + (size_t)r * 896 + c * 8) = hv;
  } else {
    // ---------------- wn_top: Wn[o][j] = bf16(pw[o][j]), j<896 ----------------
    const int item = bid - 3456;                      // 224 blocks x 1024 elems
    #pragma unroll
    for (int rr = 0; rr < 4; ++rr) {
      int idx = item * 1024 + rr * 256 + t;           // coalesced
      int o = idx / 896, j = idx % 896;
      Wn[(size_t)o * ZK + j] = f2bf(pw[(size_t)o * PROJ_IN + j]);
    }
  }
}

// ---------------------------------------------------------------------------
// MFMA GEMM, split-K=8: part[kz][b][o] = sum_{k slice} A[b][k]*Wn[o][k]
// BM=64 BN=64 BK=64; LDS 18.4 KB -> 8 blocks/CU; grid (32,4,8)=1024 blocks,
// ALL co-resident (4/CU) -> latency hidden. All-bf16 staging (A0 + Pf).
#define SAS 72    // u16 row stride: 144 B (16B-aligned rows)
__global__ __launch_bounds__(256) void gemm_kernel(
    const u16* __restrict__ A0, const u16* __restrict__ Pf,
    const u16* __restrict__ Wn, float* __restrict__ part) {
  const int bm0 = blockIdx.x * 64;
  const int bn0 = blockIdx.y * 64;
  const int kz  = blockIdx.z;
  const int it0 = kz * 10;
  const int itn = (kz == 7) ? 8 : 10;                 // 7*10+8 = 78 iters of 64
  __shared__ u16 sA[64 * SAS];                        // 9216 B
  __shared__ u16 sB[64 * SAS];                        // 9216 B
  const int t = threadIdx.x;
  const int w = t >> 6, L = t & 63;
  const int l16 = L & 15, q8 = (L >> 4) * 8;
  const int wm = (w >> 1) * 32, wn = (w & 1) * 32;    // 2x2 wave grid
  const int row = t >> 2, lk = t & 3;                 // staging: 4 thr/row, 16B x2
  f32x4 acc[2][2] = {{{0.f,0.f,0.f,0.f},{0.f,0.f,0.f,0.f}},
                     {{0.f,0.f,0.f,0.f},{0.f,0.f,0.f,0.f}}};
  u16x8 ra[2], rb[2];

#define LOAD_TILES(IT)                                                        \
  {                                                                           \
    const int k0_ = (IT) * 64;                                                \
    if (k0_ < 896) {                                                          \
      const u16* s_ = A0 + (size_t)(bm0 + row) * 896 + k0_ + lk * 8;          \
      ra[0] = *(const u16x8*)(s_);                                            \
      ra[1] = *(const u16x8*)(s_ + 32);                                       \
    } else {                                                                  \
      const int fb_ = (k0_ - 896) >> 3;                                       \
      ra[0] = *(const u16x8*)(Pf + ((size_t)(fb_ + lk) * B_ + bm0 + row) * 8);\
      ra[1] = *(const u16x8*)(Pf + ((size_t)(fb_ + 4 + lk) * B_ + bm0 + row) * 8);\
    }                                                                         \
    const u16* sb_ = Wn + (size_t)(bn0 + row) * ZK + k0_ + lk * 8;            \
    rb[0] = *(const u16x8*)(sb_);                                             \
    rb[1] = *(const u16x8*)(sb_ + 32);                                        \
  }

#define STORE_TILES()                                                         \
  {                                                                           \
    *(u16x8*)&sA[row * SAS + lk * 8]      = ra[0];                            \
    *(u16x8*)&sA[row * SAS + lk * 8 + 32] = ra[1];                            \
    *(u16x8*)&sB[row * SAS + lk * 8]      = rb[0];                            \
    *(u16x8*)&sB[row * SAS + lk * 8 + 32] = rb[1];                            \
  }

  LOAD_TILES(it0);
  for (int it = it0; it < it0 + itn; ++it) {
    __syncthreads();
    STORE_TILES();
    __syncthreads();
    if (it + 1 < it0 + itn) LOAD_TILES(it + 1);   // overlap next load with MFMA
    #pragma unroll
    for (int ks = 0; ks < 2; ++ks) {
      s16x8 a0 = *(const s16x8*)&sA[(wm + l16) * SAS + ks * 32 + q8];
      s16x8 a1 = *(const s16x8*)&sA[(wm + 16 + l16) * SAS + ks * 32 + q8];
      s16x8 b0 = *(const s16x8*)&sB[(wn + l16) * SAS + ks * 32 + q8];
      s16x8 b1 = *(const s16x8*)&sB[(wn + 16 + l16) * SAS + ks * 32 + q8];
      acc[0][0] = __builtin_amdgcn_mfma_f32_16x16x32_bf16(a0, b0, acc[0][0], 0, 0, 0);
      acc[0][1] = __builtin_amdgcn_mfma_f32_16x16x32_bf16(a0, b1, acc[0][1], 0, 0, 0);
      acc[1][0] = __builtin_amdgcn_mfma_f32_16x16x32_bf16(a1, b0, acc[1][0], 0, 0, 0);
      acc[1][1] = __builtin_amdgcn_mfma_f32_16x16x32_bf16(a1, b1, acc[1][1], 0, 0, 0);
    }
  }
#undef LOAD_TILES
#undef STORE_TILES

  float* dst = part + (size_t)kz * B_ * OUT_;
  #pragma unroll
  for (int mf = 0; mf < 2; ++mf) {
    const int r0 = bm0 + wm + mf * 16 + (L >> 4) * 4;   // C/D: col=lane&15, row=quad*4+i
    #pragma unroll
    for (int nf = 0; nf < 2; ++nf) {
      const int col = bn0 + wn + nf * 16 + l16;
      #pragma unroll
      for (int i = 0; i < 4; ++i)
        dst[(size_t)(r0 + i) * OUT_ + col] = acc[mf][nf][i];
    }
  }
}

// ---------------------------------------------------------------------------
// combine: out = relu(sum_kz part[kz] + bias), float4 per thread
__global__ __launch_bounds__(256) void combine_kernel(
    const float* __restrict__ part, const float* __restrict__ pb,
    float* __restrict__ out) {
  const int idx4 = (blockIdx.x * 256 + threadIdx.x) * 4;   // grid 512 covers B_*OUT_
  const int o = idx4 & (OUT_ - 1);
  float4 bv = *(const float4*)(pb + o);
  float4 r = bv;
  #pragma unroll
  for (int kz = 0; kz < NSPLIT; ++kz) {
    float4 a = *(const float4*)(part + (size_t)kz * B_ * OUT_ + idx4);
    r.x += a.x; r.y += a.y; r.z += a.z; r.w += a.w;
  }
  r.x = r.x > 0.f ? r.x : 0.f;
  r.y = r.y > 0.f ? r.y : 0.f;
  r.z = r.z > 0.f ? r.z : 0.f;
  r.w = r.w > 0.f ? r.w : 0.f;
  *(float4*)(out + idx4) = r;
}

// ---------------------------------------------------------------------------
extern "C" void kernel_launch(void* const* d_in, const int* in_sizes, int n_in,
                              void* d_out, int out_size, void* d_ws, size_t ws_size,
                              hipStream_t stream) {
  (void)in_sizes; (void)n_in; (void)out_size; (void)ws_size;
  const float* stat = (const float*)d_in[0];
  const float* asr  = (const float*)d_in[1];
  const float* mm   = (const float*)d_in[2];
  const float* w1   = (const float*)d_in[3];
  const float* b1   = (const float*)d_in[4];
  const float* w2   = (const float*)d_in[5];
  const float* b2   = (const float*)d_in[6];
  const float* tau  = (const float*)d_in[7];
  const float* emb  = (const float*)d_in[8];
  const float* pw   = (const float*)d_in[9];
  const float* pb   = (const float*)d_in[10];
  float* out = (float*)d_out;
  char* ws = (char*)d_ws;
  u16*   A0   = (u16*)(ws);                 //  3,670,016 B
  u16*   Pf   = (u16*)(ws + 3670016);       // 16,777,216 B
  u16*   Wn   = (u16*)(ws + 20447232);      //  2,555,904 B
  float* part = (float*)(ws + 23003136);    // 16,777,216 B

  producer_kernel<<<PRODUCER_BLOCKS, 256, 0, stream>>>(
      stat, w1, b1, w2, b2, tau, pw, emb, asr, mm, A0, Pf, Wn);
  gemm_kernel<<<dim3(B_ / 64, OUT_ / 64, NSPLIT), 256, 0, stream>>>(
      A0, Pf, Wn, part);
  combine_kernel<<<B_ * OUT_ / 1024, 256, 0, stream>>>(part, pb, out);
}

// Round 7
// 161.712 us; speedup vs baseline: 1.0685x; 1.0685x over previous
//
#include <hip/hip_runtime.h>
#include <hip/hip_bf16.h>
#include <math.h>

#define LEAKY 0.01f
#define B_    2048
#define F_    512
#define H_    64
#define K_    8
#define D_    128
#define ASR_  128
#define MM_   768
#define OUT_  256
#define PROJ_IN 66432          // 128+768+512*128
#define ZK    4992             // 896 + 512*8 (emb folded into proj_w)
#define NSPLIT 8               // gemm split-K factor

// ---------------- workspace layout (bytes) ----------------
// A0   : [B_][896]     bf16   @ 0            3,670,016   (asr|mm pre-bf16)
// Pf   : [F_][B_][8]   bf16   @ 3,670,016   16,777,216   (probs, f-major)
// Wn   : [OUT_][ZK]    bf16   @ 20,447,232   2,555,904
// part : [8][B_][OUT_] fp32   @ 23,003,136  16,777,216
// total 39,780,352

typedef unsigned short u16;
typedef u16   u16x8 __attribute__((ext_vector_type(8)));
typedef short s16x8 __attribute__((ext_vector_type(8)));
typedef float f32x4 __attribute__((ext_vector_type(4)));

__device__ __forceinline__ u16 f2bf(float x) {   // RNE float->bf16 bits
  unsigned int u = __float_as_uint(x);
  u += 0x7fffu + ((u >> 16) & 1u);
  return (u16)(u >> 16);
}

// ---------------------------------------------------------------------------
// Fused producers. Heterogeneous blocks (HBM-streamers first):
//   [0,512)      wn_g  : 8 features x 32 o-rows; pw row-chunks staged to LDS
//                        fully coalesced; emb fragment held in registers.
//   [512,1536)   probs : 4 features (wave-uniform) x 256 rows
//   [1536,2432)  a0    : asr|mm -> bf16 (2048 elems/block)
//   [2432,2656)  wn_top: bf16 copy of pw[:, :896] (1024 elems/block)
#define PRODUCER_BLOCKS (512 + 1024 + 896 + 224)
#define PWS 132   // LDS stride per feature (128 + 4): spreads banks across fl

__global__ __launch_bounds__(256) void producer_kernel(
    const float* __restrict__ stat, const float* __restrict__ w1,
    const float* __restrict__ b1v, const float* __restrict__ w2,
    const float* __restrict__ b2v, const float* __restrict__ tauv,
    const float* __restrict__ pw, const float* __restrict__ emb,
    const float* __restrict__ asr, const float* __restrict__ mm,
    u16* __restrict__ A0, u16* __restrict__ Pf, u16* __restrict__ Wn) {
  __shared__ __align__(16) char smem[15616];
  const int bid = blockIdx.x;
  const int t = threadIdx.x;

  if (bid < 512) {
    // ---------------- wn_g ----------------
    // G[f,k,o] = sum_d emb[f,k,d] * pw[o, 896+f*128+d]
    const int f0 = (bid >> 3) * 8;                    // 64 f-groups of 8
    const int o0 = (bid & 7) * 32;                    // 8 o-chunks of 32
    float* s_pw = (float*)smem;                       // [2][8*PWS] = 8448 B
    // thread -> (feature fl, k, d-quarter dq); 8k share pw via LDS broadcast
    const int fl = t >> 5, k = (t >> 2) & 7, dq = t & 3;
    // emb fragment in registers: 32 floats
    float4 e[8];
    {
      const float* ep = emb + ((size_t)(f0 + fl) * 8 + k) * 128 + dq * 32;
      #pragma unroll
      for (int j = 0; j < 8; ++j) e[j] = *(const float4*)(ep + j * 4);
    }
    // pw chunk coords: thread t loads float4 #t of the 4-KB row chunk
    const int cf = t >> 5, cd = (t & 31) * 4;         // dest f, d
    const float* pwbase = pw + 896 + (size_t)f0 * 128 + (size_t)(o0)*PROJ_IN + t * 4;
    float4 nxt = *(const float4*)(pwbase);            // row o0 (coalesced 1KB/wave)
    for (int r = 0; r < 32; ++r) {
      float* buf = s_pw + (r & 1) * (8 * PWS);
      *(float4*)(buf + cf * PWS + cd) = nxt;
      __syncthreads();
      if (r + 1 < 32) nxt = *(const float4*)(pwbase + (size_t)(r + 1) * PROJ_IN);
      const float* pp = buf + fl * PWS + dq * 32;
      float g = 0.f;
      #pragma unroll
      for (int j = 0; j < 8; ++j) {
        float4 p4 = *(const float4*)(pp + j * 4);
        g = fmaf(e[j].x, p4.x, g);
        g = fmaf(e[j].y, p4.y, g);
        g = fmaf(e[j].z, p4.z, g);
        g = fmaf(e[j].w, p4.w, g);
      }
      g += __shfl_xor(g, 1);
      g += __shfl_xor(g, 2);
      if (dq == 0)
        Wn[(size_t)(o0 + r) * ZK + 896 + (f0 + fl) * 8 + k] = f2bf(g);
    }
  } else if (bid < 1536) {
    // ---------------- probs: 4 features (1/wave) x 256 rows ----------------
    const int pb = bid - 512;
    const int f0 = (pb & 127) * 4;
    const int b0 = (pb >> 7) * 256;
    float* s_w1s = (float*)(smem);                    // [4][64]   1024 B
    float* s_b1  = (float*)(smem + 1024);             // 1024 B
    float* s_w2  = (float*)(smem + 2048);             // [4][512]  8192 B
    float* s_b2  = (float*)(smem + 10240);            // 128 B
    float* s_tau = (float*)(smem + 10368);            // 128 B
    float* s_x   = (float*)(smem + 10496);            // 256 rows x stride5 = 5120 B
    {
      int fl = t >> 6, h = t & 63;                    // 256 thr = 4 feat x 64 h
      const float* wf = w1 + (size_t)(f0 + fl) * 192;
      s_w1s[fl * 64 + h] = wf[h] + wf[64 + h] + wf[128 + h];  // x3 identical copies
      s_b1[fl * 64 + h] = b1v[(size_t)(f0 + fl) * 64 + h];
    }
    for (int i = t; i < 4 * 512; i += 256) {
      int fl = i >> 9, idx = i & 511;
      s_w2[fl * 512 + idx] = w2[(size_t)(f0 + fl) * 512 + idx];
    }
    if (t < 32) {
      s_b2[t]  = b2v[f0 * 8 + t];
      s_tau[t] = tauv[f0 * 8 + t];
    }
    for (int p = 0; p < 4; ++p) {                     // stat tile
      int i = p * 256 + t;
      int r = i >> 2, fl = i & 3;
      float v = stat[(size_t)(b0 + r) * F_ + f0 + fl];
      s_x[r * 5 + fl] = (v >= 0.f) ? v : 0.f;         // NaN -> 0, neg -> 0
    }
    __syncthreads();

    const int w = t >> 6;                             // wave-uniform feature
    const int lane = t & 63;
    const float* w1p = s_w1s + w * 64;
    const float* b1p = s_b1 + w * 64;
    const float* w2p = s_w2 + w * 512;
    float x[4];
    #pragma unroll
    for (int p = 0; p < 4; ++p) x[p] = s_x[(lane + 64 * p) * 5 + w];
    float acc[4][8] = {{0.f}};
    #pragma unroll 4
    for (int i = 0; i < 64; ++i) {
      float wv = w1p[i], bv = b1p[i];                 // broadcast reads
      float4 wa = *(const float4*)(w2p + i * 8);
      float4 wb = *(const float4*)(w2p + i * 8 + 4);
      #pragma unroll
      for (int p = 0; p < 4; ++p) {
        float h0 = fmaf(x[p], wv, bv);
        float h = fmaf(LEAKY, fminf(h0, 0.f), fmaxf(h0, 0.f));
        acc[p][0] = fmaf(h, wa.x, acc[p][0]);
        acc[p][1] = fmaf(h, wa.y, acc[p][1]);
        acc[p][2] = fmaf(h, wa.z, acc[p][2]);
        acc[p][3] = fmaf(h, wa.w, acc[p][3]);
        acc[p][4] = fmaf(h, wb.x, acc[p][4]);
        acc[p][5] = fmaf(h, wb.y, acc[p][5]);
        acc[p][6] = fmaf(h, wb.z, acc[p][6]);
        acc[p][7] = fmaf(h, wb.w, acc[p][7]);
      }
    }
    #pragma unroll
    for (int p = 0; p < 4; ++p) {
      float s[K_];
      float m = -1e30f;
      #pragma unroll
      for (int kk = 0; kk < K_; ++kk) {
        float v = acc[p][kk] + s_b2[w * 8 + kk];
        v = (v >= 0.f) ? v : LEAKY * v;
        v *= s_tau[w * 8 + kk];
        s[kk] = v;
        m = fmaxf(m, v);
      }
      float sum = 0.f;
      #pragma unroll
      for (int kk = 0; kk < K_; ++kk) { s[kk] = __expf(s[kk] - m); sum += s[kk]; }
      float inv = 1.f / sum;
      u16x8 hv;
      #pragma unroll
      for (int kk = 0; kk < K_; ++kk) hv[kk] = f2bf(s[kk] * inv);
      // Pf[f][b][8]: 64 consecutive rows/wave -> coalesced 16B stores
      *(u16x8*)(Pf + ((size_t)(f0 + w) * B_ + b0 + lane + 64 * p) * 8) = hv;
    }
  } else if (bid < 2432) {
    // ---------------- a0: A0[b][j] = bf16(asr|mm) ----------------
    const int item = bid - 1536;                      // 896 blocks x 2048 elems
    const int cidx = item * 256 + t;                  // chunk of 8; 112 chunks/row
    const int r = cidx / 112, c = cidx % 112;
    float4 v0, v1;
    if (c < 16) {
      const float* s = asr + (size_t)r * ASR_ + c * 8;
      v0 = *(const float4*)(s); v1 = *(const float4*)(s + 4);
    } else {
      const float* s = mm + (size_t)r * MM_ + (c - 16) * 8;
      v0 = *(const float4*)(s); v1 = *(const float4*)(s + 4);
    }
    u16x8 hv = {f2bf(v0.x), f2bf(v0.y), f2bf(v0.z), f2bf(v0.w),
                f2bf(v1.x), f2bf(v1.y), f2bf(v1.z), f2bf(v1.w)};
    *(u16x8*)(A0 + (size_t)r * 896 + c * 8) = hv;
  } else {
    // ---------------- wn_top: Wn[o][j] = bf16(pw[o][j]), j<896 ----------------
    const int item = bid - 2432;                      // 224 blocks x 1024 elems
    #pragma unroll
    for (int rr = 0; rr < 4; ++rr) {
      int idx = item * 1024 + rr * 256 + t;           // coalesced
      int o = idx / 896, j = idx % 896;
      Wn[(size_t)o * ZK + j] = f2bf(pw[(size_t)o * PROJ_IN + j]);
    }
  }
}

// ---------------------------------------------------------------------------
// MFMA GEMM, split-K=8: part[kz][b][o] = sum_{k slice} A[b][k]*Wn[o][k]
// BM=64 BN=64 BK=64; LDS 18.4 KB; grid (32,4,8)=1024 blocks.
// Pf staging: 32-lane groups read 512 B contiguous within one plane.
#define SAS 72    // u16 row stride: 144 B
__global__ __launch_bounds__(256) void gemm_kernel(
    const u16* __restrict__ A0, const u16* __restrict__ Pf,
    const u16* __restrict__ Wn, float* __restrict__ part) {
  const int bm0 = blockIdx.x * 64;
  const int bn0 = blockIdx.y * 64;
  const int kz  = blockIdx.z;
  const int it0 = kz * 10;
  const int itn = (kz == 7) ? 8 : 10;                 // 7*10+8 = 78 iters of 64
  __shared__ u16 sA[64 * SAS];                        // 9216 B
  __shared__ u16 sB[64 * SAS];                        // 9216 B
  const int t = threadIdx.x;
  const int w = t >> 6, L = t & 63;
  const int l16 = L & 15, q8 = (L >> 4) * 8;
  const int wm = (w >> 1) * 32, wn = (w & 1) * 32;    // 2x2 wave grid
  const int row = t >> 2, lk = t & 3;                 // A0/Wn staging coords
  const int pp = t >> 5, pg = t & 31;                 // Pf staging coords
  f32x4 acc[2][2] = {{{0.f,0.f,0.f,0.f},{0.f,0.f,0.f,0.f}},
                     {{0.f,0.f,0.f,0.f},{0.f,0.f,0.f,0.f}}};
  u16x8 ra[2], rb[2];

#define LOAD_TILES(IT)                                                        \
  {                                                                           \
    const int k0_ = (IT) * 64;                                                \
    if (k0_ < 896) {                                                          \
      const u16* s_ = A0 + (size_t)(bm0 + row) * 896 + k0_ + lk * 8;          \
      ra[0] = *(const u16x8*)(s_);                                            \
      ra[1] = *(const u16x8*)(s_ + 32);                                       \
    } else {                                                                  \
      const int fb_ = (k0_ - 896) >> 3;                                       \
      const u16* s_ = Pf + ((size_t)(fb_ + pp) * B_ + bm0 + pg) * 8;          \
      ra[0] = *(const u16x8*)(s_);                                            \
      ra[1] = *(const u16x8*)(s_ + 256);   /* +32 rows */                     \
    }                                                                         \
    const u16* sb_ = Wn + (size_t)(bn0 + row) * ZK + k0_ + lk * 8;            \
    rb[0] = *(const u16x8*)(sb_);                                             \
    rb[1] = *(const u16x8*)(sb_ + 32);                                        \
  }

#define STORE_TILES(IT)                                                       \
  {                                                                           \
    if ((IT) * 64 < 896) {                                                    \
      *(u16x8*)&sA[row * SAS + lk * 8]      = ra[0];                          \
      *(u16x8*)&sA[row * SAS + lk * 8 + 32] = ra[1];                          \
    } else {                                                                  \
      *(u16x8*)&sA[pg * SAS + pp * 8]        = ra[0];                         \
      *(u16x8*)&sA[(pg + 32) * SAS + pp * 8] = ra[1];                         \
    }                                                                         \
    *(u16x8*)&sB[row * SAS + lk * 8]      = rb[0];                            \
    *(u16x8*)&sB[row * SAS + lk * 8 + 32] = rb[1];                            \
  }

  LOAD_TILES(it0);
  for (int it = it0; it < it0 + itn; ++it) {
    __syncthreads();
    STORE_TILES(it);
    __syncthreads();
    if (it + 1 < it0 + itn) LOAD_TILES(it + 1);   // overlap next load with MFMA
    #pragma unroll
    for (int ks = 0; ks < 2; ++ks) {
      s16x8 a0 = *(const s16x8*)&sA[(wm + l16) * SAS + ks * 32 + q8];
      s16x8 a1 = *(const s16x8*)&sA[(wm + 16 + l16) * SAS + ks * 32 + q8];
      s16x8 b0 = *(const s16x8*)&sB[(wn + l16) * SAS + ks * 32 + q8];
      s16x8 b1 = *(const s16x8*)&sB[(wn + 16 + l16) * SAS + ks * 32 + q8];
      acc[0][0] = __builtin_amdgcn_mfma_f32_16x16x32_bf16(a0, b0, acc[0][0], 0, 0, 0);
      acc[0][1] = __builtin_amdgcn_mfma_f32_16x16x32_bf16(a0, b1, acc[0][1], 0, 0, 0);
      acc[1][0] = __builtin_amdgcn_mfma_f32_16x16x32_bf16(a1, b0, acc[1][0], 0, 0, 0);
      acc[1][1] = __builtin_amdgcn_mfma_f32_16x16x32_bf16(a1, b1, acc[1][1], 0, 0, 0);
    }
  }
#undef LOAD_TILES
#undef STORE_TILES

  float* dst = part + (size_t)kz * B_ * OUT_;
  #pragma unroll
  for (int mf = 0; mf < 2; ++mf) {
    const int r0 = bm0 + wm + mf * 16 + (L >> 4) * 4;   // C/D: col=lane&15, row=quad*4+i
    #pragma unroll
    for (int nf = 0; nf < 2; ++nf) {
      const int col = bn0 + wn + nf * 16 + l16;
      #pragma unroll
      for (int i = 0; i < 4; ++i)
        dst[(size_t)(r0 + i) * OUT_ + col] = acc[mf][nf][i];
    }
  }
}

// ---------------------------------------------------------------------------
// combine: out = relu(sum_kz part[kz] + bias), float4 per thread
__global__ __launch_bounds__(256) void combine_kernel(
    const float* __restrict__ part, const float* __restrict__ pb,
    float* __restrict__ out) {
  const int idx4 = (blockIdx.x * 256 + threadIdx.x) * 4;
  const int o = idx4 & (OUT_ - 1);
  float4 bv = *(const float4*)(pb + o);
  float4 r = bv;
  #pragma unroll
  for (int kz = 0; kz < NSPLIT; ++kz) {
    float4 a = *(const float4*)(part + (size_t)kz * B_ * OUT_ + idx4);
    r.x += a.x; r.y += a.y; r.z += a.z; r.w += a.w;
  }
  r.x = r.x > 0.f ? r.x : 0.f;
  r.y = r.y > 0.f ? r.y : 0.f;
  r.z = r.z > 0.f ? r.z : 0.f;
  r.w = r.w > 0.f ? r.w : 0.f;
  *(float4*)(out + idx4) = r;
}

// ---------------------------------------------------------------------------
extern "C" void kernel_launch(void* const* d_in, const int* in_sizes, int n_in,
                              void* d_out, int out_size, void* d_ws, size_t ws_size,
                              hipStream_t stream) {
  (void)in_sizes; (void)n_in; (void)out_size; (void)ws_size;
  const float* stat = (const float*)d_in[0];
  const float* asr  = (const float*)d_in[1];
  const float* mm   = (const float*)d_in[2];
  const float* w1   = (const float*)d_in[3];
  const float* b1   = (const float*)d_in[4];
  const float* w2   = (const float*)d_in[5];
  const float* b2   = (const float*)d_in[6];
  const float* tau  = (const float*)d_in[7];
  const float* emb  = (const float*)d_in[8];
  const float* pw   = (const float*)d_in[9];
  const float* pb   = (const float*)d_in[10];
  float* out = (float*)d_out;
  char* ws = (char*)d_ws;
  u16*   A0   = (u16*)(ws);                 //  3,670,016 B
  u16*   Pf   = (u16*)(ws + 3670016);       // 16,777,216 B
  u16*   Wn   = (u16*)(ws + 20447232);      //  2,555,904 B
  float* part = (float*)(ws + 23003136);    // 16,777,216 B

  producer_kernel<<<PRODUCER_BLOCKS, 256, 0, stream>>>(
      stat, w1, b1, w2, b2, tau, pw, emb, asr, mm, A0, Pf, Wn);
  gemm_kernel<<<dim3(B_ / 64, OUT_ / 64, NSPLIT), 256, 0, stream>>>(
      A0, Pf, Wn, part);
  combine_kernel<<<B_ * OUT_ / 1024, 256, 0, stream>>>(part, pb, out);
}